// Round 7
// baseline (346.679 us; speedup 1.0000x reference)
//
#include <hip/hip_runtime.h>

// B=16, C=256, H=W=64 -> N=4096, NH=4, HD=64, G=32 (8 ch/group), K=256
// ALL inputs and d_out are FP32. Internal: bf16 operands + fp32 acc.
// qkv rows: o in [0,768): q=[0,256), k=[256,512), v=[512,768)
// Workspace:
//   qkv  : (o, b*N + n) 768 x 65536 bf16 = 100,663,296 B at +0
//   ctx  : (b*4+h,e,d)  64 x 64 x 64 f32 =   1,048,576 B at +100663296
//   scsh : (b,c) float2                  =      32,768 B at +101711872
//   qst  : (o,b) float2 256x16           =      32,768 B at +101744640
//   wbf  : qkv_w bf16 768x256            =     393,216 B at +101777408
//   W2   : (b,o,c') 16x256x256 bf16 (2MB) reuses dead k-rows (+33554432)
//   kst  : (bh,n) float2 64x4096 (2MB) lives in d_out (overwritten by gemm2)
// v8: gemm cores = r5's v6 (measured best, 66 us); NEW: LDS-bounce wide
// epilogues in both gemms; k-softmax stats hoisted to kstats pass so ctx
// applies exp at stage time (5 barriers+3 serial loops -> 2 barriers).

typedef __bf16 bf16x8 __attribute__((ext_vector_type(8)));
typedef __bf16 bf16x4 __attribute__((ext_vector_type(4)));
typedef __bf16 bf16x2 __attribute__((ext_vector_type(2)));
typedef float  f32x4  __attribute__((ext_vector_type(4)));

__device__ __forceinline__ float wave_red_sum(float v) {
#pragma unroll
    for (int off = 32; off > 0; off >>= 1) v += __shfl_xor(v, off, 64);
    return v;
}
__device__ __forceinline__ float wave_red_max(float v) {
#pragma unroll
    for (int off = 32; off > 0; off >>= 1) v = fmaxf(v, __shfl_xor(v, off, 64));
    return v;
}

// ---------------------------------------------------------------------------
// GroupNorm stats -> per-channel (sc, sh); grid 512 = (b16 x g32), block 256
// wcast (qkv_w fp32 -> bf16, 196608 elems) folded in: 2 elems/thread.
// ---------------------------------------------------------------------------
__global__ __launch_bounds__(256)
void gn_stats_kernel(const float* __restrict__ x, const float* __restrict__ gw,
                     const float* __restrict__ gb, const float* __restrict__ qw,
                     float2* __restrict__ scsh, __bf16* __restrict__ wb)
{
    const int blk = blockIdx.x;
    const int b = blk >> 5, g = blk & 31;
    const int tid = threadIdx.x;
    const int lane = tid & 63, wid = tid >> 6;
    const size_t xbase = ((size_t)(b * 256 + g * 8)) * 4096;

    {
        const int ci = (blk * 256 + tid) * 2;
        if (ci < 196608) {
            const float2 f = *(const float2*)(qw + ci);
            bf16x2 t; t[0] = (__bf16)f.x; t[1] = (__bf16)f.y;
            *(bf16x2*)(wb + ci) = t;
        }
    }

    float s1 = 0.f, s2 = 0.f;
#pragma unroll
    for (int it = 0; it < 32; it++) {
        const int idx = (it * 256 + tid) * 4;
        const float4 v4 = *(const float4*)(x + xbase + idx);
        s1 += v4.x + v4.y + v4.z + v4.w;
        s2 += v4.x * v4.x + v4.y * v4.y + v4.z * v4.z + v4.w * v4.w;
    }
    __shared__ float red[8];
    float s1w = wave_red_sum(s1);
    float s2w = wave_red_sum(s2);
    if (lane == 0) { red[wid] = s1w; red[4 + wid] = s2w; }
    __syncthreads();
    const float mean = (red[0] + red[1] + red[2] + red[3]) * (1.0f / 32768.0f);
    const float ms   = (red[4] + red[5] + red[6] + red[7]) * (1.0f / 32768.0f);
    const float inv  = rsqrtf(fmaxf(ms - mean * mean, 0.f) + 1e-5f);

    if (tid < 8) {
        const int c = g * 8 + tid;
        const float sc = gw[c] * inv;
        const float sh = gb[c] - mean * sc;
        scsh[b * 256 + c] = make_float2(sc, sh);
    }
}

// ---------------------------------------------------------------------------
// gemm1: qkv[o][bn] = sum_c wbf[o][c] * gn(x)[c][bn] + bias.
// v6 core (66 us measured): B^T 64x256 staged once (GN fused, 264-elem rows);
// A: 3 m-tiles of 256 rows, per-kt chunk-swizzled LDS staging, 2 barriers/kt,
// 1-step reg prefetch. NEW v8 epilogue: bounce C via lds_a (XOR swizzle),
// 2 halves x 128 rows -> 16B coalesced qkv stores (was 64 scalar/thread/mt).
// grid 1024 n-tiles; block 256 (4 waves); LDS 52.2 KB -> 3 blocks/CU.
// ---------------------------------------------------------------------------
__global__ __launch_bounds__(256)
void gemm1_kernel(const __bf16* __restrict__ wbf,
                  const float* __restrict__ x,
                  const float* __restrict__ bias,
                  const float2* __restrict__ scsh,
                  __bf16* __restrict__ qkv)
{
    __shared__ __align__(16) __bf16 lds_bt[64 * 264];   // B^T: [n][c], 33792 B
    __shared__ __align__(16) char  lds_a[256 * 64];     // A stage / C bounce
    __shared__ float2 lscsh[256];

    const int tid  = threadIdx.x;
    const int lane = tid & 63;
    const int wid  = tid >> 6;
    const int quad = lane >> 4;
    const int tcol = lane & 15;
    const int wm   = wid * 64;        // wave's m-base within 256-row tile
    const int n0   = blockIdx.x * 64;
    const int b    = n0 >> 12;
    const int nn   = n0 & 4095;

    lscsh[tid] = scsh[b * 256 + tid];
    __syncthreads();

    // ---- stage B^T once: [n 64][c 256], GroupNorm fused; x read exactly once
    const int sn = tid & 63;
    const int cq = tid >> 6;
    const float* xs = x + (size_t)b * 1048576 + nn + sn;
#pragma unroll
    for (int iter = 0; iter < 4; iter++) {
        const int cbase = cq * 64 + iter * 16;
        bf16x8 o0, o1;
#pragma unroll
        for (int j = 0; j < 16; j++) {
            const int c = cbase + j;
            const float2 ss = lscsh[c];
            const float f = xs[(size_t)c * 4096];
            const __bf16 v = (__bf16)(f * ss.x + ss.y);
            if (j < 8) o0[j] = v; else o1[j - 8] = v;
        }
        __bf16* dst = &lds_bt[sn * 264 + cbase];
        *(bf16x8*)dst       = o0;
        *(bf16x8*)(dst + 8) = o1;
    }

    // ---- A staging geometry (r0 chunk-swizzled layout, 0 conflicts)
    const int r_   = tid >> 1;
    const int ah   = tid & 1;
    const int h16  = ah * 16;
    const int aswz = (r_ >> 1) & 3;
    const int ch0  = (((ah * 2)     + aswz) & 3) * 16;
    const int ch1  = (((ah * 2 + 1) + aswz) & 3) * 16;
    const __bf16* abase = wbf + (size_t)r_ * 256 + h16;

    bf16x8 a0 = *(const bf16x8*)(abase);
    bf16x8 a1 = *(const bf16x8*)(abase + 8);
    bf16x8 a2 = *(const bf16x8*)(abase + 32768);
    bf16x8 a3 = *(const bf16x8*)(abase + 32768 + 8);

    for (int mt = 0; mt < 3; mt++) {
        f32x4 acc[4][4];
#pragma unroll
        for (int i = 0; i < 4; i++)
#pragma unroll
            for (int j = 0; j < 4; j++) acc[i][j] = {0.f, 0.f, 0.f, 0.f};

        for (int kt = 0; kt < 256; kt += 32) {
            __syncthreads();
            *(bf16x8*)&lds_a[r_ * 64         + ch0] = a0;
            *(bf16x8*)&lds_a[r_ * 64         + ch1] = a1;
            *(bf16x8*)&lds_a[(r_ + 128) * 64 + ch0] = a2;
            *(bf16x8*)&lds_a[(r_ + 128) * 64 + ch1] = a3;
            __syncthreads();

            const int last = (kt == 224);
            const int nkt  = last ? 0 : kt + 32;
            const int nmt  = last ? mt + 1 : mt;
            if (nmt < 3) {
                const __bf16* ap = abase + (size_t)nmt * 65536 + nkt;
                a0 = *(const bf16x8*)(ap);
                a1 = *(const bf16x8*)(ap + 8);
                a2 = *(const bf16x8*)(ap + 32768);
                a3 = *(const bf16x8*)(ap + 32768 + 8);
            }

            bf16x8 af[4];
#pragma unroll
            for (int mi = 0; mi < 4; mi++) {
                const int m = wm + mi * 16 + tcol;
                af[mi] = *(const bf16x8*)&lds_a[m * 64
                         + ((quad + ((m >> 1) & 3)) & 3) * 16];
            }
            bf16x8 bfr[4];
#pragma unroll
            for (int ni = 0; ni < 4; ni++)
                bfr[ni] = *(const bf16x8*)&lds_bt[(ni * 16 + tcol) * 264
                                                 + kt + quad * 8];
#pragma unroll
            for (int mi = 0; mi < 4; mi++)
#pragma unroll
                for (int ni = 0; ni < 4; ni++)
                    acc[mi][ni] = __builtin_amdgcn_mfma_f32_16x16x32_bf16(
                        af[mi], bfr[ni], acc[mi][ni], 0, 0, 0);
        }

        // ---- v8 epilogue: bounce C through lds_a, 2 halves x 128 rows.
        // write: scalar bf16 at (row*128 + col*2) ^ ((row&7)<<4)
        // read:  bf16x8 at   (row*128 + seg*64 + j*16) ^ ((row&7)<<4)
#pragma unroll
        for (int half = 0; half < 2; half++) {
            __syncthreads();               // lds_a free (MFMAs of mt done)
            if ((wm >> 7) == half) {
                const int rbase = wm & 127;
#pragma unroll
                for (int mi = 0; mi < 4; mi++)
#pragma unroll
                    for (int r = 0; r < 4; r++) {
                        const int row  = rbase + mi * 16 + quad * 4 + r;
                        const int grow = mt * 256 + half * 128 + row;
                        const float bv = bias[grow];
#pragma unroll
                        for (int ni = 0; ni < 4; ni++) {
                            const int col  = ni * 16 + tcol;
                            const int byo  = (row * 128 + col * 2) ^ ((row & 7) << 4);
                            *(__bf16*)&lds_a[byo] = (__bf16)(acc[mi][ni][r] + bv);
                        }
                    }
            }
            __syncthreads();
            {
                const int row  = tid >> 1, seg = tid & 1;
                const int grow = mt * 256 + half * 128 + row;
                __bf16* dst = qkv + (size_t)grow * 65536 + n0 + seg * 32;
#pragma unroll
                for (int j = 0; j < 4; j++) {
                    const int byo = (row * 128 + seg * 64 + j * 16) ^ ((row & 7) << 4);
                    *(bf16x8*)(dst + j * 8) = *(const bf16x8*)&lds_a[byo];
                }
            }
        }
    }
}

// ---------------------------------------------------------------------------
// qstats: per (o,b) row of q: (max, 1/sum(exp)) -> qst[o*16+b]
// grid 4096 = (o 256) x (b 16); block 256
// ---------------------------------------------------------------------------
__global__ __launch_bounds__(256)
void qstats_kernel(const __bf16* __restrict__ qkv, float2* __restrict__ qst)
{
    const int o = blockIdx.x >> 4;
    const int b = blockIdx.x & 15;
    const int tid = threadIdx.x;
    const int lane = tid & 63, wid = tid >> 6;
    const size_t base = (size_t)o * 65536 + (size_t)b * 4096;

    float v[16];
    float m = -INFINITY;
#pragma unroll
    for (int s = 0; s < 16; s++) {
        v[s] = (float)qkv[base + s * 256 + tid];
        m = fmaxf(m, v[s]);
    }
    __shared__ float red[4];
    float wmx = wave_red_max(m);
    if (lane == 0) red[wid] = wmx;
    __syncthreads();
    m = fmaxf(fmaxf(red[0], red[1]), fmaxf(red[2], red[3]));
    __syncthreads();
    float sum = 0.f;
#pragma unroll
    for (int s = 0; s < 16; s++) sum += __expf(v[s] - m);
    float wsm = wave_red_sum(sum);
    if (lane == 0) red[wid] = wsm;
    __syncthreads();
    if (tid == 0)
        qst[o * 16 + b] = make_float2(m, 1.0f / (red[0] + red[1] + red[2] + red[3]));
}

// ---------------------------------------------------------------------------
// kstats: per (bh, n): max over d of k[d][n] and 1/sum(exp). 32 MB read.
// grid 1024 = (bh 64) x (chunk 16); block 256 (one thread per n).
// ---------------------------------------------------------------------------
__global__ __launch_bounds__(256)
void kstats_kernel(const __bf16* __restrict__ qkv, float2* __restrict__ kst)
{
    const int bh = blockIdx.x >> 4, chunk = blockIdx.x & 15;
    const int b = bh >> 2, hh = bh & 3;
    const int n = chunk * 256 + threadIdx.x;
    const __bf16* kp = qkv + (size_t)(256 + hh * 64) * 65536 + (size_t)b * 4096 + n;

    float m = -INFINITY;
    for (int d = 0; d < 64; d++)
        m = fmaxf(m, (float)kp[(size_t)d * 65536]);
    float s = 0.f;
    for (int d = 0; d < 64; d++)
        s += __expf((float)kp[(size_t)d * 65536] - m);
    kst[(size_t)bh * 4096 + n] = make_float2(m, 1.0f / s);
}

// ---------------------------------------------------------------------------
// ctx[bh][e][d] = sum_n v[e][n] * softmax_d(k)[d][n] via MFMA.
// v8: softmax stats from kst; exp applied during k staging -> 2 barriers/chunk
// (was 5 + three serial 16-loops). grid 512 = (bh 64) x (kc 8); block 256.
// ---------------------------------------------------------------------------
__global__ __launch_bounds__(256)
void ctx_mfma_kernel(const __bf16* __restrict__ qkv,
                     const float2* __restrict__ kst,
                     float* __restrict__ ctx)
{
    const int bh = blockIdx.x >> 3, kc = blockIdx.x & 7;
    const int b = bh >> 2, hh = bh & 3;
    __shared__ __align__(16) __bf16 lk[64 * 72], lv[64 * 72];
    __shared__ float2 lsmv[2][64];
    const int tid = threadIdx.x;
    const int lane = tid & 63, wid = tid >> 6;
    const int quad = lane >> 4, tcol = lane & 15;
    const int eh = (wid & 1) * 32, dh = (wid >> 1) * 32;
    const int sd = tid >> 2, snn = (tid & 3) * 16;

    f32x4 acc[2][2];
#pragma unroll
    for (int i = 0; i < 2; i++)
#pragma unroll
        for (int j = 0; j < 2; j++) acc[i][j] = {0.f, 0.f, 0.f, 0.f};

    const size_t kbase = (size_t)(256 + hh * 64) * 65536 + (size_t)b * 4096 + kc * 512;
    const size_t vbase = (size_t)(512 + hh * 64) * 65536 + (size_t)b * 4096 + kc * 512;
    const float2* kstp = kst + (size_t)bh * 4096 + kc * 512;

    if (tid < 64) lsmv[0][tid] = kstp[tid];

    for (int nc = 0; nc < 512; nc += 64) {
        const int p = (nc >> 6) & 1;
        __syncthreads();
        {   // stage k (exp fused via lsmv[p]) and v; rows = ch, stride 72
            const __bf16* ks = qkv + kbase + (size_t)sd * 65536 + nc + snn;
            const bf16x8 k0 = *(const bf16x8*)ks;
            const bf16x8 k1 = *(const bf16x8*)(ks + 8);
            bf16x8 o0, o1;
#pragma unroll
            for (int j = 0; j < 8; j++) {
                const float2 s0 = lsmv[p][snn + j];
                const float2 s1 = lsmv[p][snn + 8 + j];
                o0[j] = (__bf16)(__expf((float)k0[j] - s0.x) * s0.y);
                o1[j] = (__bf16)(__expf((float)k1[j] - s1.x) * s1.y);
            }
            *(bf16x8*)&lk[sd * 72 + snn]     = o0;
            *(bf16x8*)&lk[sd * 72 + snn + 8] = o1;
            const __bf16* vs = qkv + vbase + (size_t)sd * 65536 + nc + snn;
            *(bf16x8*)&lv[sd * 72 + snn]     = *(const bf16x8*)vs;
            *(bf16x8*)&lv[sd * 72 + snn + 8] = *(const bf16x8*)(vs + 8);
        }
        if (tid < 64 && nc + 64 < 512)
            lsmv[p ^ 1][tid] = kstp[nc + 64 + tid];
        __syncthreads();

        // MFMA: D[e][d] += sum_n v[e][n] * k_sm[d][n]
#pragma unroll
        for (int k2 = 0; k2 < 64; k2 += 32) {
            bf16x8 af[2], bfr[2];
#pragma unroll
            for (int mi = 0; mi < 2; mi++)
                af[mi] = *(const bf16x8*)&lv[(eh + mi * 16 + tcol) * 72 + k2 + quad * 8];
#pragma unroll
            for (int ni = 0; ni < 2; ni++)
                bfr[ni] = *(const bf16x8*)&lk[(dh + ni * 16 + tcol) * 72 + k2 + quad * 8];
#pragma unroll
            for (int mi = 0; mi < 2; mi++)
#pragma unroll
                for (int ni = 0; ni < 2; ni++)
                    acc[mi][ni] = __builtin_amdgcn_mfma_f32_16x16x32_bf16(
                        af[mi], bfr[ni], acc[mi][ni], 0, 0, 0);
        }
    }
    float* cb = ctx + (size_t)bh * 4096;
#pragma unroll
    for (int mi = 0; mi < 2; mi++)
#pragma unroll
        for (int ni = 0; ni < 2; ni++)
#pragma unroll
            for (int r = 0; r < 4; r++) {
                const int e = eh + mi * 16 + quad * 4 + r;
                const int d = dh + ni * 16 + tcol;
                atomicAdd(&cb[e * 64 + d], acc[mi][ni][r]);
            }
}

// ---------------------------------------------------------------------------
// W2[b][o][h*64+d] = sum_e out_w[o][h*64+e] * ctx[bh][e][d]   (bf16 out)
// grid 64 = (b 16) x (h 4); block 256 (one thread per o)
// ---------------------------------------------------------------------------
__global__ __launch_bounds__(256)
void w2_kernel(const float* __restrict__ ctx, const float* __restrict__ out_w,
               __bf16* __restrict__ w2)
{
    const int bh = blockIdx.x;
    const int b = bh >> 2, hh = bh & 3;
    const int tid = threadIdx.x;

    __shared__ __align__(16) float lctx[4096];
    const float* csrc = ctx + (size_t)bh * 4096;
#pragma unroll
    for (int i = 0; i < 4; i++)
        ((float4*)lctx)[tid + i * 256] = ((const float4*)csrc)[tid + i * 256];
    __syncthreads();

    float acc[64];
#pragma unroll
    for (int d = 0; d < 64; d++) acc[d] = 0.f;

    const float* wrow = out_w + (size_t)tid * 256 + hh * 64;
    for (int e = 0; e < 64; e++) {
        const float w = wrow[e];
#pragma unroll
        for (int d4 = 0; d4 < 64; d4 += 4) {
            const float4 c4 = *(const float4*)&lctx[e * 64 + d4];
            acc[d4 + 0] += w * c4.x;
            acc[d4 + 1] += w * c4.y;
            acc[d4 + 2] += w * c4.z;
            acc[d4 + 3] += w * c4.w;
        }
    }
    __bf16* dst = w2 + (size_t)b * 65536 + (size_t)tid * 256 + hh * 64;
#pragma unroll
    for (int d4 = 0; d4 < 64; d4 += 4) {
        bf16x4 t;
        t[0] = (__bf16)acc[d4 + 0]; t[1] = (__bf16)acc[d4 + 1];
        t[2] = (__bf16)acc[d4 + 2]; t[3] = (__bf16)acc[d4 + 3];
        *(bf16x4*)(dst + d4) = t;
    }
}

// ---------------------------------------------------------------------------
// gemm2: out[b][o][n] = sum_c W2[b][o][c] * softmax_n(q)[c][bn] + out_b + x.
// v6 core: 64-col B^T (q-softmax fused), 256-row A tile staged per-kt
// (chunk-swizzled), 2 barriers/kt, reg prefetch. NEW v8 epilogue: bounce C
// (f32) via lds_a, 4 rounds x 64 rows -> float4 residual loads + stores.
// grid 1024; block 256; LDS 52.2 KB -> 3 blocks/CU.
// ---------------------------------------------------------------------------
__global__ __launch_bounds__(256)
void gemm2_kernel(const __bf16* __restrict__ w2,
                  const __bf16* __restrict__ qkv,
                  const float2* __restrict__ qst,
                  const float* __restrict__ bias,
                  const float* __restrict__ xres,
                  float* __restrict__ out)
{
    __shared__ __align__(16) __bf16 lds_bt[64 * 264];   // B^T: [n][k], 33792 B
    __shared__ __align__(16) char  lds_a[256 * 64];     // A stage / C bounce
    __shared__ float2 lqst[256];

    const int tid  = threadIdx.x;
    const int lane = tid & 63;
    const int wid  = tid >> 6;
    const int quad = lane >> 4;
    const int tcol = lane & 15;
    const int wm   = wid * 64;
    const int n0   = blockIdx.x * 64;
    const int b    = n0 >> 12;

    lqst[tid] = qst[tid * 16 + b];
    __syncthreads();

    // ---- stage B^T once: [n 64][c 256], q-softmax fused, paired n loads
    const int pr  = tid & 31;
    const int cg  = tid >> 5;
    const int sn0 = pr * 2;
    const __bf16* qs = qkv + n0 + sn0;
#pragma unroll
    for (int cc = 0; cc < 32; cc += 8) {
        bf16x8 oe, oo;
#pragma unroll
        for (int j = 0; j < 8; j++) {
            const int c = cg * 32 + cc + j;
            const float2 qq = lqst[c];
            const bf16x2 u = *(const bf16x2*)(qs + (size_t)c * 65536);
            oe[j] = (__bf16)(__expf((float)u[0] - qq.x) * qq.y);
            oo[j] = (__bf16)(__expf((float)u[1] - qq.x) * qq.y);
        }
        *(bf16x8*)&lds_bt[sn0 * 264 + cg * 32 + cc]       = oe;
        *(bf16x8*)&lds_bt[(sn0 + 1) * 264 + cg * 32 + cc] = oo;
    }

    // ---- A staging geometry (chunk-swizzled), A = w2[b] 256x256
    const int r_   = tid >> 1;
    const int ah   = tid & 1;
    const int h16  = ah * 16;
    const int aswz = (r_ >> 1) & 3;
    const int ch0  = (((ah * 2)     + aswz) & 3) * 16;
    const int ch1  = (((ah * 2 + 1) + aswz) & 3) * 16;
    const __bf16* abase = w2 + (size_t)b * 65536 + (size_t)r_ * 256 + h16;

    bf16x8 a0 = *(const bf16x8*)(abase);
    bf16x8 a1 = *(const bf16x8*)(abase + 8);
    bf16x8 a2 = *(const bf16x8*)(abase + 32768);
    bf16x8 a3 = *(const bf16x8*)(abase + 32768 + 8);

    f32x4 acc[4][4];
#pragma unroll
    for (int i = 0; i < 4; i++)
#pragma unroll
        for (int j = 0; j < 4; j++) acc[i][j] = {0.f, 0.f, 0.f, 0.f};

    for (int kt = 0; kt < 256; kt += 32) {
        __syncthreads();
        *(bf16x8*)&lds_a[r_ * 64         + ch0] = a0;
        *(bf16x8*)&lds_a[r_ * 64         + ch1] = a1;
        *(bf16x8*)&lds_a[(r_ + 128) * 64 + ch0] = a2;
        *(bf16x8*)&lds_a[(r_ + 128) * 64 + ch1] = a3;
        __syncthreads();

        if (kt < 224) {
            const __bf16* ap = abase + kt + 32;
            a0 = *(const bf16x8*)(ap);
            a1 = *(const bf16x8*)(ap + 8);
            a2 = *(const bf16x8*)(ap + 32768);
            a3 = *(const bf16x8*)(ap + 32768 + 8);
        }

        bf16x8 af[4];
#pragma unroll
        for (int mi = 0; mi < 4; mi++) {
            const int m = wm + mi * 16 + tcol;
            af[mi] = *(const bf16x8*)&lds_a[m * 64
                     + ((quad + ((m >> 1) & 3)) & 3) * 16];
        }
        bf16x8 bfr[4];
#pragma unroll
        for (int ni = 0; ni < 4; ni++)
            bfr[ni] = *(const bf16x8*)&lds_bt[(ni * 16 + tcol) * 264
                                             + kt + quad * 8];
#pragma unroll
        for (int mi = 0; mi < 4; mi++)
#pragma unroll
            for (int ni = 0; ni < 4; ni++)
                acc[mi][ni] = __builtin_amdgcn_mfma_f32_16x16x32_bf16(
                    af[mi], bfr[ni], acc[mi][ni], 0, 0, 0);
    }

    // ---- v8 epilogue: bounce C (f32) via lds_a, 4 rounds x 64 rows.
    // write: scalar f32 at (row*256 + col*4) ^ ((row&7)<<4)
    // read:  f32x4 at    (row*256 + q*64 + j*16) ^ ((row&7)<<4)
#pragma unroll
    for (int rd = 0; rd < 4; rd++) {
        __syncthreads();
        if (wid == rd) {
#pragma unroll
            for (int mi = 0; mi < 4; mi++)
#pragma unroll
                for (int r = 0; r < 4; r++) {
                    const int row = mi * 16 + quad * 4 + r;
                    const float bv = bias[rd * 64 + row];
#pragma unroll
                    for (int ni = 0; ni < 4; ni++) {
                        const int col = ni * 16 + tcol;
                        const int byo = (row * 256 + col * 4) ^ ((row & 7) << 4);
                        *(float*)&lds_a[byo] = acc[mi][ni][r] + bv;
                    }
                }
        }
        __syncthreads();
        {
            const int row = tid >> 2, q = tid & 3;
            const int o = rd * 64 + row;
            const size_t obase = ((size_t)(b * 256 + o)) * 4096
                               + (n0 & 4095) + q * 16;
#pragma unroll
            for (int j = 0; j < 4; j++) {
                const int byo = (row * 256 + q * 64 + j * 16) ^ ((row & 7) << 4);
                const f32x4 v = *(const f32x4*)&lds_a[byo];
                const float4 xv = *(const float4*)(xres + obase + j * 4);
                float4 ov;
                ov.x = v[0] + xv.x; ov.y = v[1] + xv.y;
                ov.z = v[2] + xv.z; ov.w = v[3] + xv.w;
                *(float4*)(out + obase + j * 4) = ov;
            }
        }
    }
}

// ---------------------------------------------------------------------------
extern "C" void kernel_launch(void* const* d_in, const int* in_sizes, int n_in,
                              void* d_out, int out_size, void* d_ws, size_t ws_size,
                              hipStream_t stream)
{
    const float* x     = (const float*)d_in[0];
    const float* gn_w  = (const float*)d_in[1];
    const float* gn_b  = (const float*)d_in[2];
    const float* qkv_w = (const float*)d_in[3];
    const float* qkv_b = (const float*)d_in[4];
    const float* out_w = (const float*)d_in[5];
    const float* out_b = (const float*)d_in[6];
    float* out = (float*)d_out;

    char* ws = (char*)d_ws;
    __bf16* qkv  = (__bf16*)ws;                                   // 100,663,296 B
    float*  ctx  = (float*)(ws + (size_t)100663296);              //   1,048,576 B
    float2* scsh = (float2*)(ws + (size_t)101711872);             //      32,768 B
    float2* qst  = (float2*)(ws + (size_t)101744640);             //      32,768 B
    __bf16* wbf  = (__bf16*)(ws + (size_t)101777408);             //     393,216 B
    __bf16* w2   = qkv + (size_t)256 * 65536;                     // dead k rows
    float2* kst  = (float2*)d_out;     // 2 MB scratch; gemm2 overwrites all

    hipMemsetAsync(ctx, 0, 262144 * sizeof(float), stream);
    gn_stats_kernel<<<512, 256, 0, stream>>>(x, gn_w, gn_b, qkv_w, scsh, wbf);
    gemm1_kernel<<<1024, 256, 0, stream>>>(wbf, x, qkv_b, scsh, qkv);
    qstats_kernel<<<4096, 256, 0, stream>>>(qkv, qst);
    kstats_kernel<<<1024, 256, 0, stream>>>(qkv, kst);
    ctx_mfma_kernel<<<512, 256, 0, stream>>>(qkv, kst, ctx);
    w2_kernel<<<64, 256, 0, stream>>>(ctx, out_w, w2);
    gemm2_kernel<<<1024, 256, 0, stream>>>(w2, qkv, qst, out_b, x, out);
}

// Round 8
// 265.483 us; speedup vs baseline: 1.3058x; 1.3058x over previous
//
#include <hip/hip_runtime.h>

// B=16, C=256, H=W=64 -> N=4096, NH=4, HD=64, G=32 (8 ch/group), K=256
// ALL inputs and d_out are FP32. Internal: bf16 operands + fp32 acc.
// qkv rows: o in [0,768): q=[0,256), k=[256,512), v=[512,768)
// Workspace:
//   qkv  : (o, b*N + n) 768 x 65536 bf16 = 100,663,296 B at +0
//   ctx  : (b*4+h,e,d)  64 x 64 x 64 f32 =   1,048,576 B at +100663296
//   scsh : (b,c) float2                  =      32,768 B at +101711872
//   qst  : (o,b) float2 256x16           =      32,768 B at +101744640
//   wbf  : qkv_w bf16 768x256            =     393,216 B at +101777408
//   W2   : (b,o,c') 16x256x256 bf16 (2MB) reuses dead k-rows (+33554432)
// v9 = measured composition: gemm1 from r5 (v6 core, 66 us measured) +
// everything else from r1 (rest measured 185.4 us). No new structure.

typedef __bf16 bf16x8 __attribute__((ext_vector_type(8)));
typedef __bf16 bf16x4 __attribute__((ext_vector_type(4)));
typedef __bf16 bf16x2 __attribute__((ext_vector_type(2)));
typedef float  f32x4  __attribute__((ext_vector_type(4)));

__device__ __forceinline__ float wave_red_sum(float v) {
#pragma unroll
    for (int off = 32; off > 0; off >>= 1) v += __shfl_xor(v, off, 64);
    return v;
}
__device__ __forceinline__ float wave_red_max(float v) {
#pragma unroll
    for (int off = 32; off > 0; off >>= 1) v = fmaxf(v, __shfl_xor(v, off, 64));
    return v;
}

// ---------------------------------------------------------------------------
// GroupNorm stats -> per-channel (sc, sh); grid 512 = (b16 x g32), block 256
// wcast (qkv_w fp32 -> bf16, 196608 elems) folded in: 2 elems/thread.
// ---------------------------------------------------------------------------
__global__ __launch_bounds__(256)
void gn_stats_kernel(const float* __restrict__ x, const float* __restrict__ gw,
                     const float* __restrict__ gb, const float* __restrict__ qw,
                     float2* __restrict__ scsh, __bf16* __restrict__ wb)
{
    const int blk = blockIdx.x;
    const int b = blk >> 5, g = blk & 31;
    const int tid = threadIdx.x;
    const int lane = tid & 63, wid = tid >> 6;
    const size_t xbase = ((size_t)(b * 256 + g * 8)) * 4096;

    {
        const int ci = (blk * 256 + tid) * 2;
        if (ci < 196608) {
            const float2 f = *(const float2*)(qw + ci);
            bf16x2 t; t[0] = (__bf16)f.x; t[1] = (__bf16)f.y;
            *(bf16x2*)(wb + ci) = t;
        }
    }

    float s1 = 0.f, s2 = 0.f;
#pragma unroll
    for (int it = 0; it < 32; it++) {
        const int idx = (it * 256 + tid) * 4;
        const float4 v4 = *(const float4*)(x + xbase + idx);
        s1 += v4.x + v4.y + v4.z + v4.w;
        s2 += v4.x * v4.x + v4.y * v4.y + v4.z * v4.z + v4.w * v4.w;
    }
    __shared__ float red[8];
    float s1w = wave_red_sum(s1);
    float s2w = wave_red_sum(s2);
    if (lane == 0) { red[wid] = s1w; red[4 + wid] = s2w; }
    __syncthreads();
    const float mean = (red[0] + red[1] + red[2] + red[3]) * (1.0f / 32768.0f);
    const float ms   = (red[4] + red[5] + red[6] + red[7]) * (1.0f / 32768.0f);
    const float inv  = rsqrtf(fmaxf(ms - mean * mean, 0.f) + 1e-5f);

    if (tid < 8) {
        const int c = g * 8 + tid;
        const float sc = gw[c] * inv;
        const float sh = gb[c] - mean * sc;
        scsh[b * 256 + c] = make_float2(sc, sh);
    }
}

// ---------------------------------------------------------------------------
// gemm1 (r5 v6 core, 66 us measured): qkv[o][bn] = wbf[o][:] . gn(x)[:][bn].
// B^T 64 n x 256 c staged once (GN fused, linear 264-elem rows, ~0 conflict).
// A: 3 m-tiles of 256 rows; per-kt 256x32 tile staged to LDS chunk-swizzled
// (0 conflicts); each thread stages 4 bf16x8; 2 barriers/kt; reg prefetch.
// grid 1024 n-tiles; block 256 (4 waves); LDS 52.2 KB -> 3 blocks/CU.
// ---------------------------------------------------------------------------
__global__ __launch_bounds__(256)
void gemm1_kernel(const __bf16* __restrict__ wbf,
                  const float* __restrict__ x,
                  const float* __restrict__ bias,
                  const float2* __restrict__ scsh,
                  __bf16* __restrict__ qkv)
{
    __shared__ __align__(16) __bf16 lds_bt[64 * 264];   // B^T: [n][c], 33792 B
    __shared__ __align__(16) char  lds_a[256 * 64];     // A: chunk-swz, 16384 B
    __shared__ float2 lscsh[256];

    const int tid  = threadIdx.x;
    const int lane = tid & 63;
    const int wid  = tid >> 6;
    const int quad = lane >> 4;
    const int tcol = lane & 15;
    const int wm   = wid * 64;        // wave's m-base within 256-row tile
    const int n0   = blockIdx.x * 64;
    const int b    = n0 >> 12;
    const int nn   = n0 & 4095;

    lscsh[tid] = scsh[b * 256 + tid];
    __syncthreads();

    // ---- stage B^T once: [n 64][c 256], GroupNorm fused; x read exactly once
    const int sn = tid & 63;
    const int cq = tid >> 6;          // c-quarter 0..3 (one per wave)
    const float* xs = x + (size_t)b * 1048576 + nn + sn;
#pragma unroll
    for (int iter = 0; iter < 4; iter++) {
        const int cbase = cq * 64 + iter * 16;
        bf16x8 o0, o1;
#pragma unroll
        for (int j = 0; j < 16; j++) {
            const int c = cbase + j;
            const float2 ss = lscsh[c];
            const float f = xs[(size_t)c * 4096];
            const __bf16 v = (__bf16)(f * ss.x + ss.y);
            if (j < 8) o0[j] = v; else o1[j - 8] = v;
        }
        __bf16* dst = &lds_bt[sn * 264 + cbase];
        *(bf16x8*)dst       = o0;
        *(bf16x8*)(dst + 8) = o1;
    }

    // ---- A staging geometry (r0 chunk-swizzled layout, 0 conflicts)
    const int r_   = tid >> 1;
    const int ah   = tid & 1;
    const int h16  = ah * 16;
    const int aswz = (r_ >> 1) & 3;
    const int ch0  = (((ah * 2)     + aswz) & 3) * 16;
    const int ch1  = (((ah * 2 + 1) + aswz) & 3) * 16;
    const __bf16* abase = wbf + (size_t)r_ * 256 + h16;

    bf16x8 a0 = *(const bf16x8*)(abase);
    bf16x8 a1 = *(const bf16x8*)(abase + 8);
    bf16x8 a2 = *(const bf16x8*)(abase + 32768);
    bf16x8 a3 = *(const bf16x8*)(abase + 32768 + 8);

    for (int mt = 0; mt < 3; mt++) {
        f32x4 acc[4][4];
#pragma unroll
        for (int i = 0; i < 4; i++)
#pragma unroll
            for (int j = 0; j < 4; j++) acc[i][j] = {0.f, 0.f, 0.f, 0.f};

        for (int kt = 0; kt < 256; kt += 32) {
            __syncthreads();
            *(bf16x8*)&lds_a[r_ * 64         + ch0] = a0;
            *(bf16x8*)&lds_a[r_ * 64         + ch1] = a1;
            *(bf16x8*)&lds_a[(r_ + 128) * 64 + ch0] = a2;
            *(bf16x8*)&lds_a[(r_ + 128) * 64 + ch1] = a3;
            __syncthreads();

            const int last = (kt == 224);
            const int nkt  = last ? 0 : kt + 32;
            const int nmt  = last ? mt + 1 : mt;
            if (nmt < 3) {
                const __bf16* ap = abase + (size_t)nmt * 65536 + nkt;
                a0 = *(const bf16x8*)(ap);
                a1 = *(const bf16x8*)(ap + 8);
                a2 = *(const bf16x8*)(ap + 32768);
                a3 = *(const bf16x8*)(ap + 32768 + 8);
            }

            bf16x8 af[4];
#pragma unroll
            for (int mi = 0; mi < 4; mi++) {
                const int m = wm + mi * 16 + tcol;
                af[mi] = *(const bf16x8*)&lds_a[m * 64
                         + ((quad + ((m >> 1) & 3)) & 3) * 16];
            }
            bf16x8 bfr[4];
#pragma unroll
            for (int ni = 0; ni < 4; ni++)
                bfr[ni] = *(const bf16x8*)&lds_bt[(ni * 16 + tcol) * 264
                                                 + kt + quad * 8];
#pragma unroll
            for (int mi = 0; mi < 4; mi++)
#pragma unroll
                for (int ni = 0; ni < 4; ni++)
                    acc[mi][ni] = __builtin_amdgcn_mfma_f32_16x16x32_bf16(
                        af[mi], bfr[ni], acc[mi][ni], 0, 0, 0);
        }

        // epilogue: C/D layout col = lane&15 (N), row = quad*4 + r (M)
#pragma unroll
        for (int mi = 0; mi < 4; mi++) {
#pragma unroll
            for (int r = 0; r < 4; r++) {
                const int grow = mt * 256 + wm + mi * 16 + quad * 4 + r;
                const float bv = bias[grow];
#pragma unroll
                for (int ni = 0; ni < 4; ni++) {
                    const int gcol = n0 + ni * 16 + tcol;
                    qkv[(size_t)grow * 65536 + gcol] = (__bf16)(acc[mi][ni][r] + bv);
                }
            }
        }
    }
}

// ---------------------------------------------------------------------------
// qstats: per (o,b) row of q: (max, 1/sum(exp)) -> qst[o*16+b]
// grid 4096 = (o 256) x (b 16); block 256
// ---------------------------------------------------------------------------
__global__ __launch_bounds__(256)
void qstats_kernel(const __bf16* __restrict__ qkv, float2* __restrict__ qst)
{
    const int o = blockIdx.x >> 4;
    const int b = blockIdx.x & 15;
    const int tid = threadIdx.x;
    const int lane = tid & 63, wid = tid >> 6;
    const size_t base = (size_t)o * 65536 + (size_t)b * 4096;

    float v[16];
    float m = -INFINITY;
#pragma unroll
    for (int s = 0; s < 16; s++) {
        v[s] = (float)qkv[base + s * 256 + tid];
        m = fmaxf(m, v[s]);
    }
    __shared__ float red[4];
    float wmx = wave_red_max(m);
    if (lane == 0) red[wid] = wmx;
    __syncthreads();
    m = fmaxf(fmaxf(red[0], red[1]), fmaxf(red[2], red[3]));
    __syncthreads();
    float sum = 0.f;
#pragma unroll
    for (int s = 0; s < 16; s++) sum += __expf(v[s] - m);
    float wsm = wave_red_sum(sum);
    if (lane == 0) red[wid] = wsm;
    __syncthreads();
    if (tid == 0)
        qst[o * 16 + b] = make_float2(m, 1.0f / (red[0] + red[1] + red[2] + red[3]));
}

// ---------------------------------------------------------------------------
// ctx[bh][e][d] = sum_n v[e][n] * softmax_d(k)[d][n] via MFMA.
// grid 512 = (bh 64) x (kc 8); block 256 (4 waves, each owns a 32x32 quadrant)
// ---------------------------------------------------------------------------
__global__ __launch_bounds__(256)
void ctx_mfma_kernel(const __bf16* __restrict__ qkv, float* __restrict__ ctx)
{
    const int bh = blockIdx.x >> 3, kc = blockIdx.x & 7;
    const int b = bh >> 2, hh = bh & 3;
    __shared__ __align__(16) __bf16 lk[64 * 72], lv[64 * 72];
    __shared__ float smax[4][64], ssum[4][64];
    const int tid = threadIdx.x;
    const int lane = tid & 63, wid = tid >> 6;
    const int quad = lane >> 4, tcol = lane & 15;
    const int eh = (wid & 1) * 32, dh = (wid >> 1) * 32;
    const int col = tid & 63, dq = tid >> 6;
    const int sd = tid >> 2, snn = (tid & 3) * 16;

    f32x4 acc[2][2];
#pragma unroll
    for (int i = 0; i < 2; i++)
#pragma unroll
        for (int j = 0; j < 2; j++) acc[i][j] = {0.f, 0.f, 0.f, 0.f};

    const size_t kbase = (size_t)(256 + hh * 64) * 65536 + (size_t)b * 4096 + kc * 512;
    const size_t vbase = (size_t)(512 + hh * 64) * 65536 + (size_t)b * 4096 + kc * 512;

    for (int nc = 0; nc < 512; nc += 64) {
        __syncthreads();
        {   // stage k,v tiles [64 ch][64 n], row stride 72
            const __bf16* ks = qkv + kbase + (size_t)sd * 65536 + nc + snn;
            *(bf16x8*)&lk[sd * 72 + snn]     = *(const bf16x8*)ks;
            *(bf16x8*)&lk[sd * 72 + snn + 8] = *(const bf16x8*)(ks + 8);
            const __bf16* vs = qkv + vbase + (size_t)sd * 65536 + nc + snn;
            *(bf16x8*)&lv[sd * 72 + snn]     = *(const bf16x8*)vs;
            *(bf16x8*)&lv[sd * 72 + snn + 8] = *(const bf16x8*)(vs + 8);
        }
        __syncthreads();

        // fused k-softmax over d (full d=64 in tile per column)
        float kvv[16];
        float pm = -INFINITY;
#pragma unroll
        for (int i = 0; i < 16; i++) {
            kvv[i] = (float)lk[(dq * 16 + i) * 72 + col];
            pm = fmaxf(pm, kvv[i]);
        }
        smax[dq][col] = pm;
        __syncthreads();
        const float m = fmaxf(fmaxf(smax[0][col], smax[1][col]),
                              fmaxf(smax[2][col], smax[3][col]));
        float ps = 0.f;
#pragma unroll
        for (int i = 0; i < 16; i++) { kvv[i] = __expf(kvv[i] - m); ps += kvv[i]; }
        ssum[dq][col] = ps;
        __syncthreads();
        const float inv = 1.0f / (ssum[0][col] + ssum[1][col] + ssum[2][col] + ssum[3][col]);
#pragma unroll
        for (int i = 0; i < 16; i++)
            lk[(dq * 16 + i) * 72 + col] = (__bf16)(kvv[i] * inv);
        __syncthreads();

        // MFMA: D[e][d] += sum_n v[e][n] * k_sm[d][n]
#pragma unroll
        for (int k2 = 0; k2 < 64; k2 += 32) {
            bf16x8 af[2], bfr[2];
#pragma unroll
            for (int mi = 0; mi < 2; mi++)
                af[mi] = *(const bf16x8*)&lv[(eh + mi * 16 + tcol) * 72 + k2 + quad * 8];
#pragma unroll
            for (int ni = 0; ni < 2; ni++)
                bfr[ni] = *(const bf16x8*)&lk[(dh + ni * 16 + tcol) * 72 + k2 + quad * 8];
#pragma unroll
            for (int mi = 0; mi < 2; mi++)
#pragma unroll
                for (int ni = 0; ni < 2; ni++)
                    acc[mi][ni] = __builtin_amdgcn_mfma_f32_16x16x32_bf16(
                        af[mi], bfr[ni], acc[mi][ni], 0, 0, 0);
        }
    }
    float* cb = ctx + (size_t)bh * 4096;
#pragma unroll
    for (int mi = 0; mi < 2; mi++)
#pragma unroll
        for (int ni = 0; ni < 2; ni++)
#pragma unroll
            for (int r = 0; r < 4; r++) {
                const int e = eh + mi * 16 + quad * 4 + r;
                const int d = dh + ni * 16 + tcol;
                atomicAdd(&cb[e * 64 + d], acc[mi][ni][r]);
            }
}

// ---------------------------------------------------------------------------
// W2[b][o][h*64+d] = sum_e out_w[o][h*64+e] * ctx[bh][e][d]   (bf16 out)
// grid 64 = (b 16) x (h 4); block 256 (one thread per o)
// ---------------------------------------------------------------------------
__global__ __launch_bounds__(256)
void w2_kernel(const float* __restrict__ ctx, const float* __restrict__ out_w,
               __bf16* __restrict__ w2)
{
    const int bh = blockIdx.x;
    const int b = bh >> 2, hh = bh & 3;
    const int tid = threadIdx.x;

    __shared__ __align__(16) float lctx[4096];
    const float* csrc = ctx + (size_t)bh * 4096;
#pragma unroll
    for (int i = 0; i < 4; i++)
        ((float4*)lctx)[tid + i * 256] = ((const float4*)csrc)[tid + i * 256];
    __syncthreads();

    float acc[64];
#pragma unroll
    for (int d = 0; d < 64; d++) acc[d] = 0.f;

    const float* wrow = out_w + (size_t)tid * 256 + hh * 64;
    for (int e = 0; e < 64; e++) {
        const float w = wrow[e];
#pragma unroll
        for (int d4 = 0; d4 < 64; d4 += 4) {
            const float4 c4 = *(const float4*)&lctx[e * 64 + d4];
            acc[d4 + 0] += w * c4.x;
            acc[d4 + 1] += w * c4.y;
            acc[d4 + 2] += w * c4.z;
            acc[d4 + 3] += w * c4.w;
        }
    }
    __bf16* dst = w2 + (size_t)b * 65536 + (size_t)tid * 256 + hh * 64;
#pragma unroll
    for (int d4 = 0; d4 < 64; d4 += 4) {
        bf16x4 t;
        t[0] = (__bf16)acc[d4 + 0]; t[1] = (__bf16)acc[d4 + 1];
        t[2] = (__bf16)acc[d4 + 2]; t[3] = (__bf16)acc[d4 + 3];
        *(bf16x4*)(dst + d4) = t;
    }
}

// ---------------------------------------------------------------------------
// gemm2 (r1 form, part of best measured rest): out = W2 . softmax_n(q) + res.
// Full-K B^T 128x264 in LDS (chunk-swizzled, q-softmax fused), lds_a 128x40
// per-kt staging, MT=2. grid 512 n-tiles; block 256.
// ---------------------------------------------------------------------------
__global__ __launch_bounds__(256)
void gemm2_kernel(const __bf16* __restrict__ w2,
                  const __bf16* __restrict__ qkv,
                  const float2* __restrict__ qst,
                  const float* __restrict__ bias,
                  const float* __restrict__ xres,
                  float* __restrict__ out)
{
    __shared__ __align__(16) __bf16 lds_bt[128 * 264];  // B^T: [n][k], 67584 B
    __shared__ __align__(16) __bf16 lds_a[128 * 40];    // A:   [m][k], 10240 B
    __shared__ float2 lqst[256];

    const int tid  = threadIdx.x;
    const int lane = tid & 63;
    const int wid  = tid >> 6;
    const int quad = lane >> 4;
    const int tcol = lane & 15;
    const int wm   = (wid & 1) * 64;
    const int wn   = (wid >> 1) * 64;
    const int n0   = blockIdx.x * 128;
    const int b    = n0 >> 12;

    lqst[tid] = qst[tid * 16 + b];
    __syncthreads();

    const int sn    = tid & 127;
    const int chalf = tid >> 7;
    const int swz   = (sn >> 3) & 3;
#pragma unroll
    for (int iter = 0; iter < 8; iter++) {
        const int cbase = iter * 32 + chalf * 16;
        bf16x8 o0, o1;
        const __bf16* qs = qkv + n0 + sn;
#pragma unroll
        for (int j = 0; j < 16; j++) {
            const int c = cbase + j;
            const float2 qq = lqst[c];
            const float f = (float)qs[(size_t)c * 65536];
            const __bf16 v = (__bf16)(__expf(f - qq.x) * qq.y);
            if (j < 8) o0[j] = v; else o1[j - 8] = v;
        }
        const int chunk = iter * 2 + chalf;
        const int chSw  = chunk ^ swz;
        __bf16* dst = &lds_bt[sn * 264 + chSw * 16];
        *(bf16x8*)dst       = o0;
        *(bf16x8*)(dst + 8) = o1;
    }

    const int arow = tid >> 1, k16 = (tid & 1) * 16;

    for (int mt = 0; mt < 2; mt++) {
        const int m0 = mt * 128;
        f32x4 acc[4][4];
#pragma unroll
        for (int i = 0; i < 4; i++)
#pragma unroll
            for (int j = 0; j < 4; j++) acc[i][j] = {0.f, 0.f, 0.f, 0.f};

        for (int kt = 0; kt < 256; kt += 32) {
            __syncthreads();
            {   // stage A tile 128x32 from W2[b] (bf16)
                const __bf16* src = w2 + (size_t)b * 65536
                                  + (size_t)(m0 + arow) * 256 + kt + k16;
                const bf16x8 o0 = *(const bf16x8*)(src);
                const bf16x8 o1 = *(const bf16x8*)(src + 8);
                *(bf16x8*)&lds_a[arow * 40 + k16]     = o0;
                *(bf16x8*)&lds_a[arow * 40 + k16 + 8] = o1;
            }
            __syncthreads();

            bf16x8 af[4];
#pragma unroll
            for (int mi = 0; mi < 4; mi++)
                af[mi] = *(const bf16x8*)&lds_a[(wm + mi * 16 + tcol) * 40 + quad * 8];
            bf16x8 bfr[4];
#pragma unroll
            for (int ni = 0; ni < 4; ni++) {
                const int n = wn + ni * 16 + tcol;
                const int k = kt + quad * 8;
                const int chSw = (k >> 4) ^ ((n >> 3) & 3);
                bfr[ni] = *(const bf16x8*)&lds_bt[n * 264 + chSw * 16 + (k & 15)];
            }
#pragma unroll
            for (int mi = 0; mi < 4; mi++)
#pragma unroll
                for (int ni = 0; ni < 4; ni++)
                    acc[mi][ni] = __builtin_amdgcn_mfma_f32_16x16x32_bf16(
                        af[mi], bfr[ni], acc[mi][ni], 0, 0, 0);
        }

#pragma unroll
        for (int mi = 0; mi < 4; mi++) {
#pragma unroll
            for (int r = 0; r < 4; r++) {
                const int grow = m0 + wm + mi * 16 + quad * 4 + r;
                const float bv = bias[grow];
#pragma unroll
                for (int ni = 0; ni < 4; ni++) {
                    const int gcol = n0 + wn + ni * 16 + tcol;
                    const int n = gcol & 4095;
                    const size_t oidx = ((size_t)(b * 256 + grow)) * 4096 + n;
                    out[oidx] = acc[mi][ni][r] + bv + xres[oidx];
                }
            }
        }
    }
}

// ---------------------------------------------------------------------------
extern "C" void kernel_launch(void* const* d_in, const int* in_sizes, int n_in,
                              void* d_out, int out_size, void* d_ws, size_t ws_size,
                              hipStream_t stream)
{
    const float* x     = (const float*)d_in[0];
    const float* gn_w  = (const float*)d_in[1];
    const float* gn_b  = (const float*)d_in[2];
    const float* qkv_w = (const float*)d_in[3];
    const float* qkv_b = (const float*)d_in[4];
    const float* out_w = (const float*)d_in[5];
    const float* out_b = (const float*)d_in[6];
    float* out = (float*)d_out;

    char* ws = (char*)d_ws;
    __bf16* qkv  = (__bf16*)ws;                                   // 100,663,296 B
    float*  ctx  = (float*)(ws + (size_t)100663296);              //   1,048,576 B
    float2* scsh = (float2*)(ws + (size_t)101711872);             //      32,768 B
    float2* qst  = (float2*)(ws + (size_t)101744640);             //      32,768 B
    __bf16* wbf  = (__bf16*)(ws + (size_t)101777408);             //     393,216 B
    __bf16* w2   = qkv + (size_t)256 * 65536;                     // dead k rows

    hipMemsetAsync(ctx, 0, 262144 * sizeof(float), stream);
    gn_stats_kernel<<<512, 256, 0, stream>>>(x, gn_w, gn_b, qkv_w, scsh, wbf);
    gemm1_kernel<<<1024, 256, 0, stream>>>(wbf, x, qkv_b, scsh, qkv);
    qstats_kernel<<<4096, 256, 0, stream>>>(qkv, qst);
    ctx_mfma_kernel<<<512, 256, 0, stream>>>(qkv, ctx);
    w2_kernel<<<64, 256, 0, stream>>>(ctx, out_w, w2);
    gemm2_kernel<<<512, 256, 0, stream>>>(w2, qkv, qst, out_b, x, out);
}